// Round 9
// baseline (520.182 us; speedup 1.0000x reference)
//
#include <hip/hip_runtime.h>
#include <hip/hip_bf16.h>
#include <stdint.h>

typedef __hip_bfloat16 bf16;
typedef __attribute__((ext_vector_type(8))) short bf16x8;  // MFMA A/B frag (4 VGPRs)
typedef __attribute__((ext_vector_type(4))) float f32x4;   // MFMA C/D frag

__device__ __forceinline__ bf16x8 ldsv8(const bf16* p) { return *(const bf16x8*)p; }

__device__ __forceinline__ short bf_bits(float f) {
  union { bf16 h; short s; } u; u.h = __float2bfloat16(f); return u.s;
}

// Runtime dtype sniff: true if buffer holds bf16 (vs fp32).
__device__ __forceinline__ bool is_bf16(const void* p) {
  const uint32_t* w = (const uint32_t*)p;
  int cnt = 0;
#pragma unroll 8
  for (int i = 0; i < 64; ++i) {
    uint32_t e = (w[i] >> 7) & 0xffu;
    cnt += (e >= 100u && e <= 150u) ? 1 : 0;
  }
  return cnt >= 40;
}

__device__ __forceinline__ float load_f32(const void* p, size_t idx, bool b16) {
  return b16 ? __bfloat162float(((const bf16*)p)[idx]) : ((const float*)p)[idx];
}

// ---------------- convert + transpose: out[c][r] = bf16(in[r][c]) ----------------
__global__ __launch_bounds__(256) void cvtT_k(const void* __restrict__ in,
                                              bf16* __restrict__ out,
                                              int R, int Ccols) {
  __shared__ __align__(16) bf16 tile[32][33];
  const bool b16 = is_bf16(in);
  int tx = threadIdx.x & 31, ty = threadIdx.x >> 5;
  int c0 = blockIdx.x * 32, r0 = blockIdx.y * 32;
#pragma unroll
  for (int i = 0; i < 32; i += 8)
    tile[ty + i][tx] = __float2bfloat16(load_f32(in, (size_t)(r0 + ty + i) * Ccols + c0 + tx, b16));
  __syncthreads();
#pragma unroll
  for (int i = 0; i < 32; i += 8)
    out[(size_t)(c0 + ty + i) * R + r0 + tx] = tile[tx][ty + i];
}

// ---------------- 128x128 MFMA GEMM, A[M,1024] x BT[N,1024] ----------------
// MODE 0: A = raw x (dual dtype); cols<2048 -> qk[mg][2048] (Q x0.125);
//         cols>=2048 -> V scattered to vt[bh][d][s] (quirky reshape map).
// MODE 1: A = bf16 Yb, out = FLOAT32 [M][1024] -> d_out.
template <int MODE>
__global__ __launch_bounds__(256) void gemm128(
    const void* __restrict__ Araw, const bf16* __restrict__ BT,
    const void* __restrict__ biasraw, void* __restrict__ out0,
    bf16* __restrict__ out1) {
  constexpr int K = 1024;
  __shared__ __align__(16) bf16 As[128 * 32];
  __shared__ __align__(16) bf16 Bs[128 * 32];
  const int tid = threadIdx.x;
  const int wave = tid >> 6, lane = tid & 63;
  const int quad = lane >> 4, l16 = lane & 15;
  const int m0 = blockIdx.x * 128, n0 = blockIdx.y * 128;
  const int wm = (wave & 1) * 64, wn = (wave >> 1) * 64;
  const bool a16 = (MODE == 0) ? is_bf16(Araw) : true;
  const bool bias16 = is_bf16(biasraw);

  f32x4 acc[4][4] = {};

  for (int kt = 0; kt < K; kt += 32) {
    __syncthreads();
#pragma unroll
    for (int i = 0; i < 2; ++i) {
      int slot = i * 256 + tid;
      int row = slot >> 2, col = (slot & 3) << 3;
      if (MODE != 0 || a16) {
        const bf16* ap = ((const bf16*)Araw) + (size_t)(m0 + row) * K + kt + col;
        *(bf16x8*)(As + slot * 8) = *(const bf16x8*)ap;
      } else {
        const float* ap = ((const float*)Araw) + (size_t)(m0 + row) * K + kt + col;
        float4 f0 = *(const float4*)ap;
        float4 f1 = *(const float4*)(ap + 4);
        bf16x8 pk = {bf_bits(f0.x), bf_bits(f0.y), bf_bits(f0.z), bf_bits(f0.w),
                     bf_bits(f1.x), bf_bits(f1.y), bf_bits(f1.z), bf_bits(f1.w)};
        *(bf16x8*)(As + slot * 8) = pk;
      }
      *(bf16x8*)(Bs + slot * 8) = *(const bf16x8*)(BT + (size_t)(n0 + row) * K + kt + col);
    }
    __syncthreads();
    bf16x8 af[4], bfr[4];
#pragma unroll
    for (int i = 0; i < 4; ++i)
      af[i] = ldsv8(As + (wm + i * 16 + l16) * 32 + quad * 8);
#pragma unroll
    for (int j = 0; j < 4; ++j)
      bfr[j] = ldsv8(Bs + (wn + j * 16 + l16) * 32 + quad * 8);
#pragma unroll
    for (int i = 0; i < 4; ++i)
#pragma unroll
      for (int j = 0; j < 4; ++j)
        acc[i][j] = __builtin_amdgcn_mfma_f32_16x16x32_bf16(af[i], bfr[j], acc[i][j], 0, 0, 0);
  }

  float biasf[4];
#pragma unroll
  for (int j = 0; j < 4; ++j)
    biasf[j] = load_f32(biasraw, n0 + wn + j * 16 + l16, bias16);

#pragma unroll
  for (int i = 0; i < 4; ++i)
#pragma unroll
    for (int j = 0; j < 4; ++j) {
      int ng = n0 + wn + j * 16 + l16;
#pragma unroll
      for (int r = 0; r < 4; ++r) {
        int mg = m0 + wm + i * 16 + quad * 4 + r;  // C/D: row=quad*4+reg, col=l16
        float v = acc[i][j][r] + biasf[j];
        if (MODE == 1) {
          ((float*)out0)[(size_t)mg * 1024 + ng] = v;  // final output fp32
        } else if (ng < 2048) {
          ((bf16*)out0)[(size_t)mg * 2048 + ng] =
              __float2bfloat16(ng < 1024 ? v * 0.125f : v);
        } else {  // V -> VT[bh][d][s] (quirky reshape: h=t>>7, s=(t&127)*16+cv/64)
          int b = mg >> 11, t = mg & 2047, cv = ng - 2048;
          int h = t >> 7, s = ((t & 127) << 4) + (cv >> 6), d = cv & 63;
          out1[((size_t)(b * 16 + h) * 64 + d) * 2048 + s] = __float2bfloat16(v);
        }
      }
    }
}

// ---------------- MFMA flash causal attention ----------------
// qk [4096][2048]: Q cols 0..1023 (x0.125), K cols 1024..2047, quirky head map:
//   head-row (h,sp) at row h*128+(sp>>4), col (sp&15)*64.  vt: [bh][d][s].
// grid (32 q-tiles of 64 rows, 32 bh); 4 waves x 16 rows.
__global__ __launch_bounds__(256) void attn_k(const bf16* __restrict__ qkb,
                                              const bf16* __restrict__ vtb,
                                              bf16* __restrict__ Yb) {
  __shared__ __align__(16) bf16 Ks[128 * 76];      // [s][d], stride 76
  __shared__ __align__(16) bf16 VTs[64 * 132];     // [d][s], stride 132
  __shared__ __align__(16) bf16 Ps[4 * 16 * 140];  // per-wave P round-trip

  const int tid = threadIdx.x;
  const int wave = tid >> 6, lane = tid & 63;
  const int quad = lane >> 4, l16 = lane & 15;
  const int qt = 31 - (int)blockIdx.x;  // heavy q-tiles first
  const int bh = blockIdx.y, b = bh >> 4, h = bh & 15;
  const size_t rowbase = (size_t)(b * 2048 + h * 128) * 2048;
  const bf16* vth = vtb + (size_t)bh * 131072;
  const int q0 = qt * 64, wrow0 = wave * 16;

  bf16x8 aq[2];  // Q frags persist (A-layout: m=l16, k=quad*8+j)
  {
    int sg = q0 + wrow0 + l16;
    const bf16* qp = qkb + rowbase + (size_t)(sg >> 4) * 2048 + ((sg & 15) << 6);
#pragma unroll
    for (int ks = 0; ks < 2; ++ks)
      aq[ks] = *(const bf16x8*)(qp + ks * 32 + quad * 8);
  }

  f32x4 o[4] = {};
  float mrow[4], lrow[4];
#pragma unroll
  for (int r = 0; r < 4; ++r) { mrow[r] = -1e30f; lrow[r] = 0.f; }

  bf16* Pw = Ps + wave * (16 * 140);
  const int stmax = qt >> 1;

  for (int st = 0; st <= stmax; ++st) {
    const int s0 = st * 128;
    __syncthreads();
#pragma unroll
    for (int i = 0; i < 4; ++i) {
      int slot = i * 256 + tid;
      // K tile: 128 s-rows x 8 d-chunks
      int row = slot >> 3, c = slot & 7, sg = s0 + row;
      *(bf16x8*)(Ks + row * 76 + c * 8) =
          *(const bf16x8*)(qkb + rowbase + (size_t)(sg >> 4) * 2048 + ((sg & 15) << 6) + 1024 + c * 8);
      // V^T tile: 64 d-rows x 16 s-chunks (vector loads from global VT)
      int d = slot >> 4, cv = slot & 15;
      *(bf16x8*)(VTs + d * 132 + cv * 8) =
          *(const bf16x8*)(vth + (size_t)d * 2048 + s0 + cv * 8);
    }
    __syncthreads();

    // S = Q K^T (Q pre-scaled)
    f32x4 s[8] = {};
#pragma unroll
    for (int ks = 0; ks < 2; ++ks)
#pragma unroll
      for (int j = 0; j < 8; ++j) {
        bf16x8 bk = ldsv8(Ks + (j * 16 + l16) * 76 + (ks * 4 + quad) * 8);
        s[j] = __builtin_amdgcn_mfma_f32_16x16x32_bf16(aq[ks], bk, s[j], 0, 0, 0);
      }

    const bool diag = (st == stmax);
#pragma unroll
    for (int r = 0; r < 4; ++r) {
      const int rglob = q0 + wrow0 + quad * 4 + r;
      float vals[8];
      float mx = -1e30f;
#pragma unroll
      for (int j = 0; j < 8; ++j) {
        float v = s[j][r];
        if (diag && (s0 + j * 16 + l16) > rglob) v = -1e30f;  // causal mask
        vals[j] = v;
        mx = fmaxf(mx, v);
      }
#pragma unroll
      for (int d = 1; d < 16; d <<= 1) mx = fmaxf(mx, __shfl_xor(mx, d, 64));
      float mnew = fmaxf(mrow[r], mx);
      float alpha = __expf(mrow[r] - mnew);
      mrow[r] = mnew;
      float rs = 0.f;
#pragma unroll
      for (int j = 0; j < 8; ++j) {
        float p = __expf(vals[j] - mnew);
        vals[j] = p;
        rs += p;
      }
#pragma unroll
      for (int d = 1; d < 16; d <<= 1) rs += __shfl_xor(rs, d, 64);
      lrow[r] = lrow[r] * alpha + rs;
#pragma unroll
      for (int j = 0; j < 4; ++j) o[j][r] *= alpha;
      bf16* prow = Pw + (quad * 4 + r) * 140;
#pragma unroll
      for (int j = 0; j < 8; ++j) prow[j * 16 + l16] = __float2bfloat16(vals[j]);
    }
    // PV (wave-private P; same-wave DS ops are in-order)
#pragma unroll
    for (int ks = 0; ks < 4; ++ks) {
      bf16x8 ap = ldsv8(Pw + l16 * 140 + ks * 32 + quad * 8);
#pragma unroll
      for (int j = 0; j < 4; ++j) {
        bf16x8 bv = ldsv8(VTs + (j * 16 + l16) * 132 + (ks * 4 + quad) * 8);
        o[j] = __builtin_amdgcn_mfma_f32_16x16x32_bf16(ap, bv, o[j], 0, 0, 0);
      }
    }
  }

  bf16* Yh = Yb + (size_t)b * 2097152 + h * 64;  // Y[b][t][h*64+d]
#pragma unroll
  for (int r = 0; r < 4; ++r) {
    int t = q0 + wrow0 + quad * 4 + r;
    float inv = 1.f / lrow[r];
#pragma unroll
    for (int j = 0; j < 4; ++j)
      Yh[(size_t)t * 1024 + j * 16 + l16] = __float2bfloat16(o[j][r] * inv);
  }
}

extern "C" void kernel_launch(void* const* d_in, const int* in_sizes, int n_in,
                              void* d_out, int out_size, void* d_ws, size_t ws_size,
                              hipStream_t stream) {
  (void)out_size; (void)ws_size;
  const void* px     = d_in[0];
  const void* pWqkv  = (n_in > 1) ? d_in[1] : d_in[0];
  const void* pbqkv  = (n_in > 2) ? d_in[2] : d_in[0];
  const void* pWproj = (n_in > 3) ? d_in[3] : d_in[0];
  const void* pbproj = (n_in > 4) ? d_in[4] : d_in[0];
  for (int i = 0; i < n_in; ++i) {
    switch (in_sizes[i]) {
      case 4194304: px     = d_in[i]; break;
      case 3145728: pWqkv  = d_in[i]; break;
      case 3072:    pbqkv  = d_in[i]; break;
      case 1048576: pWproj = d_in[i]; break;
      case 1024:    pbproj = d_in[i]; break;
      default: break;
    }
  }

  // ws layout, peak 35.65 MB (proven footprint):
  //   QK     [0,        16777216) bf16 [4096][2048], live k2..k4
  //   VT     [16777216, 25165824) bf16 [32][64][2048], live k2..k4
  //   WqkvT  [25165824, 31457280) live k1..k2
  //   WprojT [25165824, 27262976) live k3..k5 (over dead WqkvT)
  //   Yb     [27262976, 35651584) bf16 [4096][1024], live k4..k5
  char* ws = (char*)d_ws;
  bf16* qkb    = (bf16*)(ws + 0);
  bf16* vtb    = (bf16*)(ws + 16777216);
  bf16* WqkvT  = (bf16*)(ws + 25165824);
  bf16* WprojT = (bf16*)(ws + 25165824);
  bf16* Yb     = (bf16*)(ws + 27262976);

  cvtT_k<<<dim3(96, 32), 256, 0, stream>>>(pWqkv, WqkvT, 1024, 3072);              // k1
  gemm128<0><<<dim3(32, 24), 256, 0, stream>>>(px, WqkvT, pbqkv, qkb, vtb);        // k2
  cvtT_k<<<dim3(32, 32), 256, 0, stream>>>(pWproj, WprojT, 1024, 1024);            // k3
  attn_k<<<dim3(32, 32), 256, 0, stream>>>(qkb, vtb, Yb);                          // k4
  gemm128<1><<<dim3(32, 8), 256, 0, stream>>>(Yb, WprojT, pbproj, d_out, nullptr); // k5
}

// Round 10
// 483.152 us; speedup vs baseline: 1.0766x; 1.0766x over previous
//
#include <hip/hip_runtime.h>
#include <hip/hip_bf16.h>
#include <stdint.h>

typedef __hip_bfloat16 bf16;
typedef __attribute__((ext_vector_type(8))) short bf16x8;  // MFMA A/B frag (4 VGPRs)
typedef __attribute__((ext_vector_type(4))) float f32x4;   // MFMA C/D frag

__device__ __forceinline__ bf16x8 ldsv8(const bf16* p) { return *(const bf16x8*)p; }

__device__ __forceinline__ short bf_bits(float f) {
  union { bf16 h; short s; } u; u.h = __float2bfloat16(f); return u.s;
}

// Runtime dtype sniff: true if buffer holds bf16 (vs fp32).
__device__ __forceinline__ bool is_bf16(const void* p) {
  const uint32_t* w = (const uint32_t*)p;
  int cnt = 0;
#pragma unroll 8
  for (int i = 0; i < 64; ++i) {
    uint32_t e = (w[i] >> 7) & 0xffu;
    cnt += (e >= 100u && e <= 150u) ? 1 : 0;
  }
  return cnt >= 40;
}

__device__ __forceinline__ float load_f32(const void* p, size_t idx, bool b16) {
  return b16 ? __bfloat162float(((const bf16*)p)[idx]) : ((const float*)p)[idx];
}

// ---------------- convert + transpose: out[c][r] = bf16(in[r][c]) ----------------
__global__ __launch_bounds__(256) void cvtT_k(const void* __restrict__ in,
                                              bf16* __restrict__ out,
                                              int R, int Ccols) {
  __shared__ __align__(16) bf16 tile[32][33];
  const bool b16 = is_bf16(in);
  int tx = threadIdx.x & 31, ty = threadIdx.x >> 5;
  int c0 = blockIdx.x * 32, r0 = blockIdx.y * 32;
#pragma unroll
  for (int i = 0; i < 32; i += 8)
    tile[ty + i][tx] = __float2bfloat16(load_f32(in, (size_t)(r0 + ty + i) * Ccols + c0 + tx, b16));
  __syncthreads();
#pragma unroll
  for (int i = 0; i < 32; i += 8)
    out[(size_t)(c0 + ty + i) * R + r0 + tx] = tile[tx][ty + i];
}

// ---------------- 128x128 MFMA GEMM, A[M,1024] x BT[N,1024] ----------------
// MODE 0: cols<2048 -> qk[mg][2048] (Q x0.125); cols>=2048 -> V to vt[bh][d][s].
// MODE 1: A = bf16 Yb, out = FLOAT32 [M][1024] -> d_out.
template <int MODE>
__global__ __launch_bounds__(256) void gemm128(
    const void* __restrict__ Araw, const bf16* __restrict__ BT,
    const void* __restrict__ biasraw, void* __restrict__ out0,
    bf16* __restrict__ out1) {
  constexpr int K = 1024;
  __shared__ __align__(16) bf16 As[128 * 32];
  __shared__ __align__(16) bf16 Bs[128 * 32];
  const int tid = threadIdx.x;
  const int wave = tid >> 6, lane = tid & 63;
  const int quad = lane >> 4, l16 = lane & 15;
  const int m0 = blockIdx.x * 128, n0 = blockIdx.y * 128;
  const int wm = (wave & 1) * 64, wn = (wave >> 1) * 64;
  const bool a16 = (MODE == 0) ? is_bf16(Araw) : true;
  const bool bias16 = is_bf16(biasraw);

  f32x4 acc[4][4] = {};

  for (int kt = 0; kt < K; kt += 32) {
    __syncthreads();
#pragma unroll
    for (int i = 0; i < 2; ++i) {
      int slot = i * 256 + tid;
      int row = slot >> 2, col = (slot & 3) << 3;
      if (MODE != 0 || a16) {
        const bf16* ap = ((const bf16*)Araw) + (size_t)(m0 + row) * K + kt + col;
        *(bf16x8*)(As + slot * 8) = *(const bf16x8*)ap;
      } else {
        const float* ap = ((const float*)Araw) + (size_t)(m0 + row) * K + kt + col;
        float4 f0 = *(const float4*)ap;
        float4 f1 = *(const float4*)(ap + 4);
        bf16x8 pk = {bf_bits(f0.x), bf_bits(f0.y), bf_bits(f0.z), bf_bits(f0.w),
                     bf_bits(f1.x), bf_bits(f1.y), bf_bits(f1.z), bf_bits(f1.w)};
        *(bf16x8*)(As + slot * 8) = pk;
      }
      *(bf16x8*)(Bs + slot * 8) = *(const bf16x8*)(BT + (size_t)(n0 + row) * K + kt + col);
    }
    __syncthreads();
    bf16x8 af[4], bfr[4];
#pragma unroll
    for (int i = 0; i < 4; ++i)
      af[i] = ldsv8(As + (wm + i * 16 + l16) * 32 + quad * 8);
#pragma unroll
    for (int j = 0; j < 4; ++j)
      bfr[j] = ldsv8(Bs + (wn + j * 16 + l16) * 32 + quad * 8);
#pragma unroll
    for (int i = 0; i < 4; ++i)
#pragma unroll
      for (int j = 0; j < 4; ++j)
        acc[i][j] = __builtin_amdgcn_mfma_f32_16x16x32_bf16(af[i], bfr[j], acc[i][j], 0, 0, 0);
  }

  float biasf[4];
#pragma unroll
  for (int j = 0; j < 4; ++j)
    biasf[j] = load_f32(biasraw, n0 + wn + j * 16 + l16, bias16);

#pragma unroll
  for (int i = 0; i < 4; ++i)
#pragma unroll
    for (int j = 0; j < 4; ++j) {
      int ng = n0 + wn + j * 16 + l16;
#pragma unroll
      for (int r = 0; r < 4; ++r) {
        int mg = m0 + wm + i * 16 + quad * 4 + r;  // C/D: row=quad*4+reg, col=l16
        float v = acc[i][j][r] + biasf[j];
        if (MODE == 1) {
          ((float*)out0)[(size_t)mg * 1024 + ng] = v;  // final output fp32
        } else if (ng < 2048) {
          ((bf16*)out0)[(size_t)mg * 2048 + ng] =
              __float2bfloat16(ng < 1024 ? v * 0.125f : v);
        } else {  // V -> VT[bh][d][s] (quirky reshape: h=t>>7, s=(t&127)*16+cv/64)
          int b = mg >> 11, t = mg & 2047, cv = ng - 2048;
          int h = t >> 7, s = ((t & 127) << 4) + (cv >> 6), d = cv & 63;
          out1[((size_t)(b * 16 + h) * 64 + d) * 2048 + s] = __float2bfloat16(v);
        }
      }
    }
}

// ---------------- MFMA flash causal attention ----------------
// qk [4096][2048]: Q cols 0..1023 (x0.125), K cols 1024..2047, quirky head map:
//   head-row (h,sp) at row h*128+(sp>>4), col (sp&15)*64.  vt: [bh][d][s].
// grid (16 q-tiles of 128 rows, 32 bh); 4 waves x 32 rows (2 i-tiles).
// Register-prefetched KV staging; l folded into PV via ones-column MFMA.
__global__ __launch_bounds__(256) void attn_k(const bf16* __restrict__ qkb,
                                              const bf16* __restrict__ vtb,
                                              bf16* __restrict__ Yb) {
  __shared__ __align__(16) bf16 Ks[128 * 76];      // [s][d], stride 76
  __shared__ __align__(16) bf16 VTs[64 * 132];     // [d][s], stride 132
  __shared__ __align__(16) bf16 Ps[4 * 16 * 140];  // per-wave P round-trip

  const int tid = threadIdx.x;
  const int wave = tid >> 6, lane = tid & 63;
  const int quad = lane >> 4, l16 = lane & 15;
  const int qt = 15 - (int)blockIdx.x;  // heavy q-tiles first
  const int bh = blockIdx.y, b = bh >> 4, h = bh & 15;
  const size_t rowbase = (size_t)(b * 2048 + h * 128) * 2048;
  const bf16* vth = vtb + (size_t)bh * 131072;
  const int q0 = qt * 128, wrow0 = wave * 32;

  // staging slot mapping (constant per thread)
  int krow[4], kc[4], vd[4], vc[4];
#pragma unroll
  for (int i = 0; i < 4; ++i) {
    int slot = i * 256 + tid;
    krow[i] = slot >> 3; kc[i] = slot & 7;
    vd[i] = slot >> 4;  vc[i] = slot & 15;
  }

  bf16x8 aq[2][2];  // Q frags persist (A-layout: m=l16, k=quad*8+j)
#pragma unroll
  for (int i = 0; i < 2; ++i) {
    int sg = q0 + wrow0 + i * 16 + l16;
    const bf16* qp = qkb + rowbase + (size_t)(sg >> 4) * 2048 + ((sg & 15) << 6);
#pragma unroll
    for (int ks = 0; ks < 2; ++ks)
      aq[ks][i] = *(const bf16x8*)(qp + ks * 32 + quad * 8);
  }

  // ones-column B frag: B_ext[k][n=l16] = (l16==0), folds rowsum(P) into PV.
  bf16x8 onesf;
  {
    short ob = (l16 == 0) ? bf_bits(1.0f) : (short)0;
#pragma unroll
    for (int j = 0; j < 8; ++j) onesf[j] = ob;
  }

  f32x4 o[2][5] = {};  // [i][0..3]=O columns, [i][4]=l (ones column)
  float mrow[2][4];
#pragma unroll
  for (int i = 0; i < 2; ++i)
#pragma unroll
    for (int r = 0; r < 4; ++r) mrow[i][r] = -1e30f;

  bf16* Pw = Ps + wave * (16 * 140);

  // prefetch tile 0 into registers
  bf16x8 kreg[4], vreg[4];
#pragma unroll
  for (int i = 0; i < 4; ++i) {
    int sg = krow[i];
    kreg[i] = *(const bf16x8*)(qkb + rowbase + (size_t)(sg >> 4) * 2048 + ((sg & 15) << 6) + 1024 + kc[i] * 8);
    vreg[i] = *(const bf16x8*)(vth + (size_t)vd[i] * 2048 + vc[i] * 8);
  }

  for (int st = 0; st <= qt; ++st) {
    __syncthreads();  // prior compute done reading LDS
#pragma unroll
    for (int i = 0; i < 4; ++i) {
      *(bf16x8*)(Ks + krow[i] * 76 + kc[i] * 8) = kreg[i];
      *(bf16x8*)(VTs + vd[i] * 132 + vc[i] * 8) = vreg[i];
    }
    __syncthreads();
    if (st < qt) {  // prefetch next tile (latency hidden behind compute)
      const int s1 = (st + 1) * 128;
#pragma unroll
      for (int i = 0; i < 4; ++i) {
        int sg = s1 + krow[i];
        kreg[i] = *(const bf16x8*)(qkb + rowbase + (size_t)(sg >> 4) * 2048 + ((sg & 15) << 6) + 1024 + kc[i] * 8);
        vreg[i] = *(const bf16x8*)(vth + (size_t)vd[i] * 2048 + s1 + vc[i] * 8);
      }
    }

    const int s0 = st * 128;
    const bool diag = (st == qt);
#pragma unroll
    for (int i = 0; i < 2; ++i) {
      // S = Q K^T for this 16-row i-tile
      f32x4 s[8] = {};
#pragma unroll
      for (int ks = 0; ks < 2; ++ks)
#pragma unroll
        for (int j = 0; j < 8; ++j) {
          bf16x8 bk = ldsv8(Ks + (j * 16 + l16) * 76 + (ks * 4 + quad) * 8);
          s[j] = __builtin_amdgcn_mfma_f32_16x16x32_bf16(aq[ks][i], bk, s[j], 0, 0, 0);
        }
      // online softmax (no sum-chain: l folded into PV via ones column)
#pragma unroll
      for (int r = 0; r < 4; ++r) {
        const int rloc = wrow0 + i * 16 + quad * 4 + r;
        float vals[8];
        float mx = -1e30f;
#pragma unroll
        for (int j = 0; j < 8; ++j) {
          float v = s[j][r];
          if (diag && (j * 16 + l16) > rloc) v = -1e30f;  // causal mask
          vals[j] = v;
          mx = fmaxf(mx, v);
        }
#pragma unroll
        for (int d = 1; d < 16; d <<= 1) mx = fmaxf(mx, __shfl_xor(mx, d, 64));
        float mnew = fmaxf(mrow[i][r], mx);
        float alpha = __expf(mrow[i][r] - mnew);
        mrow[i][r] = mnew;
#pragma unroll
        for (int j = 0; j < 5; ++j) o[i][j][r] *= alpha;  // rescale O and l
        bf16* prow = Pw + (quad * 4 + r) * 140;
#pragma unroll
        for (int j = 0; j < 8; ++j)
          prow[j * 16 + l16] = __float2bfloat16(__expf(vals[j] - mnew));
      }
      // PV + ones column (wave-private P; same-wave DS ops in-order)
#pragma unroll
      for (int ks = 0; ks < 4; ++ks) {
        bf16x8 ap = ldsv8(Pw + l16 * 140 + ks * 32 + quad * 8);
#pragma unroll
        for (int j = 0; j < 4; ++j) {
          bf16x8 bv = ldsv8(VTs + (j * 16 + l16) * 132 + (ks * 4 + quad) * 8);
          o[i][j] = __builtin_amdgcn_mfma_f32_16x16x32_bf16(ap, bv, o[i][j], 0, 0, 0);
        }
        o[i][4] = __builtin_amdgcn_mfma_f32_16x16x32_bf16(ap, onesf, o[i][4], 0, 0, 0);
      }
    }
  }

  bf16* Yh = Yb + (size_t)b * 2097152 + h * 64;  // Y[b][t][h*64+d]
#pragma unroll
  for (int i = 0; i < 2; ++i)
#pragma unroll
    for (int r = 0; r < 4; ++r) {
      int t = q0 + wrow0 + i * 16 + quad * 4 + r;
      float l = __shfl(o[i][4][r], lane & 48, 64);  // l lives in col 0 lanes
      float inv = 1.f / l;
#pragma unroll
      for (int j = 0; j < 4; ++j)
        Yh[(size_t)t * 1024 + j * 16 + l16] = __float2bfloat16(o[i][j][r] * inv);
    }
}

extern "C" void kernel_launch(void* const* d_in, const int* in_sizes, int n_in,
                              void* d_out, int out_size, void* d_ws, size_t ws_size,
                              hipStream_t stream) {
  (void)out_size; (void)ws_size;
  const void* px     = d_in[0];
  const void* pWqkv  = (n_in > 1) ? d_in[1] : d_in[0];
  const void* pbqkv  = (n_in > 2) ? d_in[2] : d_in[0];
  const void* pWproj = (n_in > 3) ? d_in[3] : d_in[0];
  const void* pbproj = (n_in > 4) ? d_in[4] : d_in[0];
  for (int i = 0; i < n_in; ++i) {
    switch (in_sizes[i]) {
      case 4194304: px     = d_in[i]; break;
      case 3145728: pWqkv  = d_in[i]; break;
      case 3072:    pbqkv  = d_in[i]; break;
      case 1048576: pWproj = d_in[i]; break;
      case 1024:    pbproj = d_in[i]; break;
      default: break;
    }
  }

  // ws layout, peak 35.65 MB (proven footprint):
  //   QK     [0,        16777216) bf16 [4096][2048], live k2..k4
  //   VT     [16777216, 25165824) bf16 [32][64][2048], live k2..k4
  //   WqkvT  [25165824, 31457280) live k1..k2
  //   WprojT [25165824, 27262976) live k3..k5 (over dead WqkvT)
  //   Yb     [27262976, 35651584) bf16 [4096][1024], live k4..k5
  char* ws = (char*)d_ws;
  bf16* qkb    = (bf16*)(ws + 0);
  bf16* vtb    = (bf16*)(ws + 16777216);
  bf16* WqkvT  = (bf16*)(ws + 25165824);
  bf16* WprojT = (bf16*)(ws + 25165824);
  bf16* Yb     = (bf16*)(ws + 27262976);

  cvtT_k<<<dim3(96, 32), 256, 0, stream>>>(pWqkv, WqkvT, 1024, 3072);              // k1
  gemm128<0><<<dim3(32, 24), 256, 0, stream>>>(px, WqkvT, pbqkv, qkb, vtb);        // k2
  cvtT_k<<<dim3(32, 32), 256, 0, stream>>>(pWproj, WprojT, 1024, 1024);            // k3
  attn_k<<<dim3(16, 32), 256, 0, stream>>>(qkb, vtb, Yb);                          // k4
  gemm128<1><<<dim3(32, 8), 256, 0, stream>>>(Yb, WprojT, pbproj, d_out, nullptr); // k5
}

// Round 11
// 482.046 us; speedup vs baseline: 1.0791x; 1.0023x over previous
//
#include <hip/hip_runtime.h>
#include <hip/hip_bf16.h>
#include <stdint.h>

typedef __hip_bfloat16 bf16;
typedef __attribute__((ext_vector_type(8))) short bf16x8;  // MFMA A/B frag (4 VGPRs)
typedef __attribute__((ext_vector_type(4))) float f32x4;   // MFMA C/D frag

__device__ __forceinline__ bf16x8 ldsv8(const bf16* p) { return *(const bf16x8*)p; }

__device__ __forceinline__ short bf_bits(float f) {
  union { bf16 h; short s; } u; u.h = __float2bfloat16(f); return u.s;
}

// Runtime dtype sniff: true if buffer holds bf16 (vs fp32).
__device__ __forceinline__ bool is_bf16(const void* p) {
  const uint32_t* w = (const uint32_t*)p;
  int cnt = 0;
#pragma unroll 8
  for (int i = 0; i < 64; ++i) {
    uint32_t e = (w[i] >> 7) & 0xffu;
    cnt += (e >= 100u && e <= 150u) ? 1 : 0;
  }
  return cnt >= 40;
}

__device__ __forceinline__ float load_f32(const void* p, size_t idx, bool b16) {
  return b16 ? __bfloat162float(((const bf16*)p)[idx]) : ((const float*)p)[idx];
}

// ---------------- convert + transpose: out[c][r] = bf16(in[r][c]) ----------------
__global__ __launch_bounds__(256) void cvtT_k(const void* __restrict__ in,
                                              bf16* __restrict__ out,
                                              int R, int Ccols) {
  __shared__ __align__(16) bf16 tile[32][33];
  const bool b16 = is_bf16(in);
  int tx = threadIdx.x & 31, ty = threadIdx.x >> 5;
  int c0 = blockIdx.x * 32, r0 = blockIdx.y * 32;
#pragma unroll
  for (int i = 0; i < 32; i += 8)
    tile[ty + i][tx] = __float2bfloat16(load_f32(in, (size_t)(r0 + ty + i) * Ccols + c0 + tx, b16));
  __syncthreads();
#pragma unroll
  for (int i = 0; i < 32; i += 8)
    out[(size_t)(c0 + ty + i) * R + r0 + tx] = tile[tx][ty + i];
}

// ---------------- 128x128 MFMA GEMM, A[M,1024] x BT[N,1024] ----------------
// MODE 0: cols<2048 -> qk[mg][2048] (Q x0.125); cols>=2048 -> V scattered to
//         TILE-MAJOR vt[bh][st][d][sl] (st = s>>7, sl = s&127): each attention
//         KV tile is a contiguous 16 KB block (kills the 4 KB-stride L2 alias).
// MODE 1: A = bf16 Yb, out = FLOAT32 [M][1024] -> d_out.
template <int MODE>
__global__ __launch_bounds__(256) void gemm128(
    const void* __restrict__ Araw, const bf16* __restrict__ BT,
    const void* __restrict__ biasraw, void* __restrict__ out0,
    bf16* __restrict__ out1) {
  constexpr int K = 1024;
  __shared__ __align__(16) bf16 As[128 * 32];
  __shared__ __align__(16) bf16 Bs[128 * 32];
  const int tid = threadIdx.x;
  const int wave = tid >> 6, lane = tid & 63;
  const int quad = lane >> 4, l16 = lane & 15;
  const int m0 = blockIdx.x * 128, n0 = blockIdx.y * 128;
  const int wm = (wave & 1) * 64, wn = (wave >> 1) * 64;
  const bool a16 = (MODE == 0) ? is_bf16(Araw) : true;
  const bool bias16 = is_bf16(biasraw);

  f32x4 acc[4][4] = {};

  for (int kt = 0; kt < K; kt += 32) {
    __syncthreads();
#pragma unroll
    for (int i = 0; i < 2; ++i) {
      int slot = i * 256 + tid;
      int row = slot >> 2, col = (slot & 3) << 3;
      if (MODE != 0 || a16) {
        const bf16* ap = ((const bf16*)Araw) + (size_t)(m0 + row) * K + kt + col;
        *(bf16x8*)(As + slot * 8) = *(const bf16x8*)ap;
      } else {
        const float* ap = ((const float*)Araw) + (size_t)(m0 + row) * K + kt + col;
        float4 f0 = *(const float4*)ap;
        float4 f1 = *(const float4*)(ap + 4);
        bf16x8 pk = {bf_bits(f0.x), bf_bits(f0.y), bf_bits(f0.z), bf_bits(f0.w),
                     bf_bits(f1.x), bf_bits(f1.y), bf_bits(f1.z), bf_bits(f1.w)};
        *(bf16x8*)(As + slot * 8) = pk;
      }
      *(bf16x8*)(Bs + slot * 8) = *(const bf16x8*)(BT + (size_t)(n0 + row) * K + kt + col);
    }
    __syncthreads();
    bf16x8 af[4], bfr[4];
#pragma unroll
    for (int i = 0; i < 4; ++i)
      af[i] = ldsv8(As + (wm + i * 16 + l16) * 32 + quad * 8);
#pragma unroll
    for (int j = 0; j < 4; ++j)
      bfr[j] = ldsv8(Bs + (wn + j * 16 + l16) * 32 + quad * 8);
#pragma unroll
    for (int i = 0; i < 4; ++i)
#pragma unroll
      for (int j = 0; j < 4; ++j)
        acc[i][j] = __builtin_amdgcn_mfma_f32_16x16x32_bf16(af[i], bfr[j], acc[i][j], 0, 0, 0);
  }

  float biasf[4];
#pragma unroll
  for (int j = 0; j < 4; ++j)
    biasf[j] = load_f32(biasraw, n0 + wn + j * 16 + l16, bias16);

#pragma unroll
  for (int i = 0; i < 4; ++i)
#pragma unroll
    for (int j = 0; j < 4; ++j) {
      int ng = n0 + wn + j * 16 + l16;
#pragma unroll
      for (int r = 0; r < 4; ++r) {
        int mg = m0 + wm + i * 16 + quad * 4 + r;  // C/D: row=quad*4+reg, col=l16
        float v = acc[i][j][r] + biasf[j];
        if (MODE == 1) {
          ((float*)out0)[(size_t)mg * 1024 + ng] = v;  // final output fp32
        } else if (ng < 2048) {
          ((bf16*)out0)[(size_t)mg * 2048 + ng] =
              __float2bfloat16(ng < 1024 ? v * 0.125f : v);
        } else {  // V -> vt[bh][s>>7][d][s&127] (quirky reshape map, tile-major)
          int b = mg >> 11, t = mg & 2047, cv = ng - 2048;
          int h = t >> 7, s = ((t & 127) << 4) + (cv >> 6), d = cv & 63;
          out1[(size_t)(b * 16 + h) * 131072 + (size_t)(s >> 7) * 8192 + d * 128 + (s & 127)] =
              __float2bfloat16(v);
        }
      }
    }
}

// ---------------- MFMA flash causal attention ----------------
// qk [4096][2048]: Q cols 0..1023 (x0.125), K cols 1024..2047, quirky head map:
//   head-row (h,sp) at row h*128+(sp>>4), col (sp&15)*64.
// vt: TILE-MAJOR [bh][st][d][sl] — one KV tile = contiguous 16 KB.
// grid (16 q-tiles of 128 rows, 32 bh); 4 waves x 32 rows (2 i-tiles).
// Register-prefetched KV staging; l folded into PV via ones-column MFMA.
__global__ __launch_bounds__(256) void attn_k(const bf16* __restrict__ qkb,
                                              const bf16* __restrict__ vtb,
                                              bf16* __restrict__ Yb) {
  __shared__ __align__(16) bf16 Ks[128 * 76];      // [s][d], stride 76
  __shared__ __align__(16) bf16 VTs[64 * 132];     // [d][s], stride 132
  __shared__ __align__(16) bf16 Ps[4 * 16 * 140];  // per-wave P round-trip

  const int tid = threadIdx.x;
  const int wave = tid >> 6, lane = tid & 63;
  const int quad = lane >> 4, l16 = lane & 15;
  const int qt = 15 - (int)blockIdx.x;  // heavy q-tiles first
  const int bh = blockIdx.y, b = bh >> 4, h = bh & 15;
  const size_t rowbase = (size_t)(b * 2048 + h * 128) * 2048;
  const bf16* vth = vtb + (size_t)bh * 131072;
  const int q0 = qt * 128, wrow0 = wave * 32;

  // staging slot mapping (constant per thread)
  int krow[4], kc[4], vd[4], vc[4];
#pragma unroll
  for (int i = 0; i < 4; ++i) {
    int slot = i * 256 + tid;
    krow[i] = slot >> 3; kc[i] = slot & 7;
    vd[i] = slot >> 4;  vc[i] = slot & 15;
  }

  bf16x8 aq[2][2];  // Q frags persist (A-layout: m=l16, k=quad*8+j)
#pragma unroll
  for (int i = 0; i < 2; ++i) {
    int sg = q0 + wrow0 + i * 16 + l16;
    const bf16* qp = qkb + rowbase + (size_t)(sg >> 4) * 2048 + ((sg & 15) << 6);
#pragma unroll
    for (int ks = 0; ks < 2; ++ks)
      aq[ks][i] = *(const bf16x8*)(qp + ks * 32 + quad * 8);
  }

  // ones-column B frag: B_ext[k][n=l16] = (l16==0), folds rowsum(P) into PV.
  bf16x8 onesf;
  {
    short ob = (l16 == 0) ? bf_bits(1.0f) : (short)0;
#pragma unroll
    for (int j = 0; j < 8; ++j) onesf[j] = ob;
  }

  f32x4 o[2][5] = {};  // [i][0..3]=O columns, [i][4]=l (ones column)
  float mrow[2][4];
#pragma unroll
  for (int i = 0; i < 2; ++i)
#pragma unroll
    for (int r = 0; r < 4; ++r) mrow[i][r] = -1e30f;

  bf16* Pw = Ps + wave * (16 * 140);

  // prefetch tile 0 into registers (V read: fully contiguous 16 KB)
  bf16x8 kreg[4], vreg[4];
#pragma unroll
  for (int i = 0; i < 4; ++i) {
    int sg = krow[i];
    kreg[i] = *(const bf16x8*)(qkb + rowbase + (size_t)(sg >> 4) * 2048 + ((sg & 15) << 6) + 1024 + kc[i] * 8);
    vreg[i] = *(const bf16x8*)(vth + (i * 256 + tid) * 8);
  }

  for (int st = 0; st <= qt; ++st) {
    __syncthreads();  // prior compute done reading LDS
#pragma unroll
    for (int i = 0; i < 4; ++i) {
      *(bf16x8*)(Ks + krow[i] * 76 + kc[i] * 8) = kreg[i];
      *(bf16x8*)(VTs + vd[i] * 132 + vc[i] * 8) = vreg[i];
    }
    __syncthreads();
    if (st < qt) {  // prefetch next tile (latency hidden behind compute)
      const int s1 = (st + 1) * 128;
      const bf16* vtile = vth + (size_t)(st + 1) * 8192;
#pragma unroll
      for (int i = 0; i < 4; ++i) {
        int sg = s1 + krow[i];
        kreg[i] = *(const bf16x8*)(qkb + rowbase + (size_t)(sg >> 4) * 2048 + ((sg & 15) << 6) + 1024 + kc[i] * 8);
        vreg[i] = *(const bf16x8*)(vtile + (i * 256 + tid) * 8);
      }
    }

    const bool diag = (st == qt);
#pragma unroll
    for (int i = 0; i < 2; ++i) {
      // S = Q K^T for this 16-row i-tile
      f32x4 s[8] = {};
#pragma unroll
      for (int ks = 0; ks < 2; ++ks)
#pragma unroll
        for (int j = 0; j < 8; ++j) {
          bf16x8 bk = ldsv8(Ks + (j * 16 + l16) * 76 + (ks * 4 + quad) * 8);
          s[j] = __builtin_amdgcn_mfma_f32_16x16x32_bf16(aq[ks][i], bk, s[j], 0, 0, 0);
        }
      // online softmax (no sum-chain: l folded into PV via ones column)
#pragma unroll
      for (int r = 0; r < 4; ++r) {
        const int rloc = wrow0 + i * 16 + quad * 4 + r;
        float vals[8];
        float mx = -1e30f;
#pragma unroll
        for (int j = 0; j < 8; ++j) {
          float v = s[j][r];
          if (diag && (j * 16 + l16) > rloc) v = -1e30f;  // causal mask
          vals[j] = v;
          mx = fmaxf(mx, v);
        }
#pragma unroll
        for (int d = 1; d < 16; d <<= 1) mx = fmaxf(mx, __shfl_xor(mx, d, 64));
        float mnew = fmaxf(mrow[i][r], mx);
        float alpha = __expf(mrow[i][r] - mnew);
        mrow[i][r] = mnew;
#pragma unroll
        for (int j = 0; j < 5; ++j) o[i][j][r] *= alpha;  // rescale O and l
        bf16* prow = Pw + (quad * 4 + r) * 140;
#pragma unroll
        for (int j = 0; j < 8; ++j)
          prow[j * 16 + l16] = __float2bfloat16(__expf(vals[j] - mnew));
      }
      // PV + ones column (wave-private P; same-wave DS ops in-order)
#pragma unroll
      for (int ks = 0; ks < 4; ++ks) {
        bf16x8 ap = ldsv8(Pw + l16 * 140 + ks * 32 + quad * 8);
#pragma unroll
        for (int j = 0; j < 4; ++j) {
          bf16x8 bv = ldsv8(VTs + (j * 16 + l16) * 132 + (ks * 4 + quad) * 8);
          o[i][j] = __builtin_amdgcn_mfma_f32_16x16x32_bf16(ap, bv, o[i][j], 0, 0, 0);
        }
        o[i][4] = __builtin_amdgcn_mfma_f32_16x16x32_bf16(ap, onesf, o[i][4], 0, 0, 0);
      }
    }
  }

  bf16* Yh = Yb + (size_t)b * 2097152 + h * 64;  // Y[b][t][h*64+d]
#pragma unroll
  for (int i = 0; i < 2; ++i)
#pragma unroll
    for (int r = 0; r < 4; ++r) {
      int t = q0 + wrow0 + i * 16 + quad * 4 + r;
      float l = __shfl(o[i][4][r], lane & 48, 64);  // l lives in col-0 lanes
      float inv = 1.f / l;
#pragma unroll
      for (int j = 0; j < 4; ++j)
        Yh[(size_t)t * 1024 + j * 16 + l16] = __float2bfloat16(o[i][j][r] * inv);
    }
}

extern "C" void kernel_launch(void* const* d_in, const int* in_sizes, int n_in,
                              void* d_out, int out_size, void* d_ws, size_t ws_size,
                              hipStream_t stream) {
  (void)out_size; (void)ws_size;
  const void* px     = d_in[0];
  const void* pWqkv  = (n_in > 1) ? d_in[1] : d_in[0];
  const void* pbqkv  = (n_in > 2) ? d_in[2] : d_in[0];
  const void* pWproj = (n_in > 3) ? d_in[3] : d_in[0];
  const void* pbproj = (n_in > 4) ? d_in[4] : d_in[0];
  for (int i = 0; i < n_in; ++i) {
    switch (in_sizes[i]) {
      case 4194304: px     = d_in[i]; break;
      case 3145728: pWqkv  = d_in[i]; break;
      case 3072:    pbqkv  = d_in[i]; break;
      case 1048576: pWproj = d_in[i]; break;
      case 1024:    pbproj = d_in[i]; break;
      default: break;
    }
  }

  // ws layout, peak 35.65 MB (proven footprint):
  //   QK     [0,        16777216) bf16 [4096][2048], live k2..k4
  //   VT     [16777216, 25165824) bf16 [32 bh][16 st][64 d][128 sl], live k2..k4
  //   WqkvT  [25165824, 31457280) live k1..k2
  //   WprojT [25165824, 27262976) live k3..k5 (over dead WqkvT)
  //   Yb     [27262976, 35651584) bf16 [4096][1024], live k4..k5
  char* ws = (char*)d_ws;
  bf16* qkb    = (bf16*)(ws + 0);
  bf16* vtb    = (bf16*)(ws + 16777216);
  bf16* WqkvT  = (bf16*)(ws + 25165824);
  bf16* WprojT = (bf16*)(ws + 25165824);
  bf16* Yb     = (bf16*)(ws + 27262976);

  cvtT_k<<<dim3(96, 32), 256, 0, stream>>>(pWqkv, WqkvT, 1024, 3072);              // k1
  gemm128<0><<<dim3(32, 24), 256, 0, stream>>>(px, WqkvT, pbqkv, qkb, vtb);        // k2
  cvtT_k<<<dim3(32, 32), 256, 0, stream>>>(pWproj, WprojT, 1024, 1024);            // k3
  attn_k<<<dim3(16, 32), 256, 0, stream>>>(qkb, vtb, Yb);                          // k4
  gemm128<1><<<dim3(32, 8), 256, 0, stream>>>(Yb, WprojT, pbproj, d_out, nullptr); // k5
}

// Round 12
// 294.140 us; speedup vs baseline: 1.7685x; 1.6388x over previous
//
#include <hip/hip_runtime.h>
#include <hip/hip_bf16.h>
#include <stdint.h>

typedef __hip_bfloat16 bf16;
typedef __attribute__((ext_vector_type(8))) short bf16x8;  // MFMA A/B frag (4 VGPRs)
typedef __attribute__((ext_vector_type(4))) float f32x4;   // MFMA C/D frag

__device__ __forceinline__ bf16x8 ldsv8(const bf16* p) { return *(const bf16x8*)p; }

__device__ __forceinline__ short bf_bits(float f) {
  union { bf16 h; short s; } u; u.h = __float2bfloat16(f); return u.s;
}

// async global->LDS, 16 B/lane. LDS dst must be wave-uniform base + lane*16,
// which our slot layout satisfies (slot = i*256 + wave*64 + lane).
#define ASYNC16(ldsdst, gsrc)                                                  \
  __builtin_amdgcn_global_load_lds(                                            \
      (const __attribute__((address_space(1))) void*)(gsrc),                   \
      (__attribute__((address_space(3))) void*)(ldsdst), 16, 0, 0)

// Runtime dtype sniff: true if buffer holds bf16 (vs fp32).
__device__ __forceinline__ bool is_bf16(const void* p) {
  const uint32_t* w = (const uint32_t*)p;
  int cnt = 0;
#pragma unroll 8
  for (int i = 0; i < 64; ++i) {
    uint32_t e = (w[i] >> 7) & 0xffu;
    cnt += (e >= 100u && e <= 150u) ? 1 : 0;
  }
  return cnt >= 40;
}

__device__ __forceinline__ float load_f32(const void* p, size_t idx, bool b16) {
  return b16 ? __bfloat162float(((const bf16*)p)[idx]) : ((const float*)p)[idx];
}

// ---------------- convert + transpose: out[c][r] = bf16(in[r][c]) ----------------
__global__ __launch_bounds__(256) void cvtT_k(const void* __restrict__ in,
                                              bf16* __restrict__ out,
                                              int R, int Ccols) {
  __shared__ __align__(16) bf16 tile[32][33];
  const bool b16 = is_bf16(in);
  int tx = threadIdx.x & 31, ty = threadIdx.x >> 5;
  int c0 = blockIdx.x * 32, r0 = blockIdx.y * 32;
#pragma unroll
  for (int i = 0; i < 32; i += 8)
    tile[ty + i][tx] = __float2bfloat16(load_f32(in, (size_t)(r0 + ty + i) * Ccols + c0 + tx, b16));
  __syncthreads();
#pragma unroll
  for (int i = 0; i < 32; i += 8)
    out[(size_t)(c0 + ty + i) * R + r0 + tx] = tile[tx][ty + i];
}

// ---------------- 128x128 MFMA GEMM, A[M,1024] x BT[N,1024] ----------------
// m97-style global_load_lds staging (width 16). MODE 0: out = bf16 xproj
// [M][3072], Q cols x0.125. MODE 1: out = FLOAT32 [M][1024] (final output).
template <int MODE>
__global__ __launch_bounds__(256) void gemm128(
    const void* __restrict__ Araw, const bf16* __restrict__ BT,
    const void* __restrict__ biasraw, void* __restrict__ outv) {
  constexpr int K = 1024;
  __shared__ __align__(16) bf16 As[128 * 32];
  __shared__ __align__(16) bf16 Bs[128 * 32];
  const int tid = threadIdx.x;
  const int wave = tid >> 6, lane = tid & 63;
  const int quad = lane >> 4, l16 = lane & 15;
  const int m0 = blockIdx.x * 128, n0 = blockIdx.y * 128;
  const int wm = (wave & 1) * 64, wn = (wave >> 1) * 64;
  const bool a16 = (MODE == 0) ? is_bf16(Araw) : true;
  const bool bias16 = is_bf16(biasraw);

  f32x4 acc[4][4] = {};

  for (int kt = 0; kt < K; kt += 32) {
    __syncthreads();
    if (MODE != 0 || a16) {
#pragma unroll
      for (int i = 0; i < 2; ++i) {
        int slot = i * 256 + tid;
        int row = slot >> 2, col = (slot & 3) << 3;
        ASYNC16(As + slot * 8, ((const bf16*)Araw) + (size_t)(m0 + row) * K + kt + col);
        ASYNC16(Bs + slot * 8, BT + (size_t)(n0 + row) * K + kt + col);
      }
    } else {  // fp32 input fallback: convert through registers
#pragma unroll
      for (int i = 0; i < 2; ++i) {
        int slot = i * 256 + tid;
        int row = slot >> 2, col = (slot & 3) << 3;
        const float* ap = ((const float*)Araw) + (size_t)(m0 + row) * K + kt + col;
        float4 f0 = *(const float4*)ap;
        float4 f1 = *(const float4*)(ap + 4);
        bf16x8 pk = {bf_bits(f0.x), bf_bits(f0.y), bf_bits(f0.z), bf_bits(f0.w),
                     bf_bits(f1.x), bf_bits(f1.y), bf_bits(f1.z), bf_bits(f1.w)};
        *(bf16x8*)(As + slot * 8) = pk;
        *(bf16x8*)(Bs + slot * 8) = *(const bf16x8*)(BT + (size_t)(n0 + row) * K + kt + col);
      }
    }
    __syncthreads();
    bf16x8 af[4], bfr[4];
#pragma unroll
    for (int i = 0; i < 4; ++i)
      af[i] = ldsv8(As + (wm + i * 16 + l16) * 32 + quad * 8);
#pragma unroll
    for (int j = 0; j < 4; ++j)
      bfr[j] = ldsv8(Bs + (wn + j * 16 + l16) * 32 + quad * 8);
#pragma unroll
    for (int i = 0; i < 4; ++i)
#pragma unroll
      for (int j = 0; j < 4; ++j)
        acc[i][j] = __builtin_amdgcn_mfma_f32_16x16x32_bf16(af[i], bfr[j], acc[i][j], 0, 0, 0);
  }

  float biasf[4];
#pragma unroll
  for (int j = 0; j < 4; ++j)
    biasf[j] = load_f32(biasraw, n0 + wn + j * 16 + l16, bias16);

#pragma unroll
  for (int i = 0; i < 4; ++i)
#pragma unroll
    for (int j = 0; j < 4; ++j) {
      int ng = n0 + wn + j * 16 + l16;
#pragma unroll
      for (int r = 0; r < 4; ++r) {
        int mg = m0 + wm + i * 16 + quad * 4 + r;  // C/D: row=quad*4+reg, col=l16
        float v = acc[i][j][r] + biasf[j];
        if (MODE == 1) {
          ((float*)outv)[(size_t)mg * 1024 + ng] = v;  // final output fp32
        } else {
          ((bf16*)outv)[(size_t)mg * 3072 + ng] =
              __float2bfloat16(ng < 1024 ? v * 0.125f : v);
        }
      }
    }
}

// ---------------- MFMA flash causal attention (EXACT R8 kernel, 143.6 us) ----------------
// Quirky reshape: head-row (h,s) of Q/K/V = 64 contiguous elems of xproj at
// row h*128+(s>>4), col (s&15)*64 (+1024 K, +2048 V). Q pre-scaled 0.125.
// grid (16 q-tiles, 32 bh); 4 waves x 32 rows.
__global__ __launch_bounds__(256) void attn_k(const bf16* __restrict__ xproj,
                                              bf16* __restrict__ Yb) {
  __shared__ __align__(16) bf16 Ks[128 * 72];      // [s][d], stride 72
  __shared__ __align__(16) bf16 VTs[64 * 136];     // [d][s], stride 136
  __shared__ __align__(16) bf16 Ps[4 * 16 * 136];  // per-wave P round-trip

  const int tid = threadIdx.x;
  const int wave = tid >> 6, lane = tid & 63;
  const int quad = lane >> 4, l16 = lane & 15;
  const int qt = (int)gridDim.x - 1 - (int)blockIdx.x;  // heavy tiles first
  const int bh = blockIdx.y, b = bh >> 4, h = bh & 15;
  const size_t rowbase = (size_t)(b * 2048 + h * 128) * 3072;
  const int q0 = qt * 128, wrow0 = wave * 32;

  bf16x8 aq[2][2];  // Q frags persist (A-layout: m=l16, k=quad*8+j)
#pragma unroll
  for (int i = 0; i < 2; ++i) {
    int sg = q0 + wrow0 + i * 16 + l16;
    const bf16* qp = xproj + rowbase + (size_t)(sg >> 4) * 3072 + ((sg & 15) << 6);
#pragma unroll
    for (int ks = 0; ks < 2; ++ks)
      aq[ks][i] = *(const bf16x8*)(qp + ks * 32 + quad * 8);
  }

  f32x4 o[2][4] = {};
  float mrow[2][4], lrow[2][4];
#pragma unroll
  for (int i = 0; i < 2; ++i)
#pragma unroll
    for (int r = 0; r < 4; ++r) { mrow[i][r] = -1e30f; lrow[i][r] = 0.f; }

  bf16* Pw = Ps + wave * (16 * 136);

  for (int st = 0; st <= qt; ++st) {
    const int s0 = st * 128;
    __syncthreads();
#pragma unroll
    for (int i = 0; i < 4; ++i) {
      int slot = i * 256 + tid;  // 1024 slots = 128 s-rows x 8 d-blocks
      int s = slot >> 3, blk = slot & 7, sg = s0 + s;
      const bf16* base = xproj + rowbase + (size_t)(sg >> 4) * 3072 + ((sg & 15) << 6);
      *(bf16x8*)(Ks + s * 72 + blk * 8) = *(const bf16x8*)(base + 1024 + blk * 8);
      bf16x8 v8 = *(const bf16x8*)(base + 2048 + blk * 8);
      const bf16* ve = (const bf16*)&v8;
#pragma unroll
      for (int j = 0; j < 8; ++j) VTs[(blk * 8 + j) * 136 + s] = ve[j];
    }
    __syncthreads();

    f32x4 s[2][8] = {};
#pragma unroll
    for (int ks = 0; ks < 2; ++ks)
#pragma unroll
      for (int j = 0; j < 8; ++j) {
        int row = j * 16 + l16;
        bf16x8 bk = ldsv8(Ks + row * 72 + (ks * 4 + quad) * 8);
#pragma unroll
        for (int i = 0; i < 2; ++i)
          s[i][j] = __builtin_amdgcn_mfma_f32_16x16x32_bf16(aq[ks][i], bk, s[i][j], 0, 0, 0);
      }

    const bool diag = (st == qt);
#pragma unroll
    for (int i = 0; i < 2; ++i) {
#pragma unroll
      for (int r = 0; r < 4; ++r) {
        const int rloc = wrow0 + i * 16 + quad * 4 + r;
        float vals[8];
        float mx = -1e30f;
#pragma unroll
        for (int j = 0; j < 8; ++j) {
          float v = s[i][j][r];
          if (diag && (j * 16 + l16) > rloc) v = -1e30f;
          vals[j] = v;
          mx = fmaxf(mx, v);
        }
#pragma unroll
        for (int d = 1; d < 16; d <<= 1) mx = fmaxf(mx, __shfl_xor(mx, d, 64));
        float mnew = fmaxf(mrow[i][r], mx);
        float alpha = __expf(mrow[i][r] - mnew);
        mrow[i][r] = mnew;
        float rs = 0.f;
#pragma unroll
        for (int j = 0; j < 8; ++j) {
          float p = __expf(vals[j] - mnew);
          vals[j] = p;
          rs += p;
        }
#pragma unroll
        for (int d = 1; d < 16; d <<= 1) rs += __shfl_xor(rs, d, 64);
        lrow[i][r] = lrow[i][r] * alpha + rs;
#pragma unroll
        for (int j = 0; j < 4; ++j) o[i][j][r] *= alpha;
        bf16* prow = Pw + (quad * 4 + r) * 136;
#pragma unroll
        for (int j = 0; j < 8; ++j) prow[j * 16 + l16] = __float2bfloat16(vals[j]);
      }
#pragma unroll
      for (int ks = 0; ks < 4; ++ks) {
        bf16x8 ap = ldsv8(Pw + l16 * 136 + ks * 32 + quad * 8);
#pragma unroll
        for (int j = 0; j < 4; ++j) {
          int d = j * 16 + l16;
          bf16x8 bv = ldsv8(VTs + d * 136 + (ks * 4 + quad) * 8);
          o[i][j] = __builtin_amdgcn_mfma_f32_16x16x32_bf16(ap, bv, o[i][j], 0, 0, 0);
        }
      }
    }
  }

  bf16* Yh = Yb + (size_t)b * 2097152 + h * 64;  // Y[b][t][h*64+d]
#pragma unroll
  for (int i = 0; i < 2; ++i)
#pragma unroll
    for (int r = 0; r < 4; ++r) {
      int t = q0 + wrow0 + i * 16 + quad * 4 + r;
      float inv = 1.f / lrow[i][r];
#pragma unroll
      for (int j = 0; j < 4; ++j)
        Yh[(size_t)t * 1024 + j * 16 + l16] = __float2bfloat16(o[i][j][r] * inv);
    }
}

extern "C" void kernel_launch(void* const* d_in, const int* in_sizes, int n_in,
                              void* d_out, int out_size, void* d_ws, size_t ws_size,
                              hipStream_t stream) {
  (void)out_size; (void)ws_size;
  const void* px     = d_in[0];
  const void* pWqkv  = (n_in > 1) ? d_in[1] : d_in[0];
  const void* pbqkv  = (n_in > 2) ? d_in[2] : d_in[0];
  const void* pWproj = (n_in > 3) ? d_in[3] : d_in[0];
  const void* pbproj = (n_in > 4) ? d_in[4] : d_in[0];
  for (int i = 0; i < n_in; ++i) {
    switch (in_sizes[i]) {
      case 4194304: px     = d_in[i]; break;
      case 3145728: pWqkv  = d_in[i]; break;
      case 3072:    pbqkv  = d_in[i]; break;
      case 1048576: pWproj = d_in[i]; break;
      case 1024:    pbproj = d_in[i]; break;
      default: break;
    }
  }

  // ws layout, peak 35.65 MB (proven footprint, = R8):
  //   xproj  [0,        25165824) bf16 [4096][3072], live k2..k4
  //   WqkvT  [25165824, 31457280) live k1..k2
  //   WprojT [25165824, 27262976) live k3..k5 (over dead WqkvT)
  //   Yb     [27262976, 35651584) bf16 [4096][1024], live k4..k5
  char* ws = (char*)d_ws;
  bf16* xproj  = (bf16*)(ws + 0);
  bf16* WqkvT  = (bf16*)(ws + 25165824);
  bf16* WprojT = (bf16*)(ws + 25165824);
  bf16* Yb     = (bf16*)(ws + 27262976);

  cvtT_k<<<dim3(96, 32), 256, 0, stream>>>(pWqkv, WqkvT, 1024, 3072);           // k1
  gemm128<0><<<dim3(32, 24), 256, 0, stream>>>(px, WqkvT, pbqkv, xproj);        // k2
  cvtT_k<<<dim3(32, 32), 256, 0, stream>>>(pWproj, WprojT, 1024, 1024);         // k3
  attn_k<<<dim3(16, 32), 256, 0, stream>>>(xproj, Yb);                          // k4
  gemm128<1><<<dim3(32, 8), 256, 0, stream>>>(Yb, WprojT, pbproj, d_out);       // k5
}